// Round 2
// baseline (3361.388 us; speedup 1.0000x reference)
//
#include <hip/hip_runtime.h>
#include <hip/hip_bf16.h>

using bf16 = __hip_bfloat16;
typedef __bf16 bf16x8 __attribute__((ext_vector_type(8)));
typedef float f32x4 __attribute__((ext_vector_type(4)));
typedef short short4v __attribute__((ext_vector_type(4)));
typedef short short8v __attribute__((ext_vector_type(8)));

#define DEV __device__ __forceinline__

// B=32, S=64, T=64 (dec uses 63), V=32000, E=256, H=512, 4H=2048

DEV unsigned short f2bf(float f) {  // RNE float->bf16
  unsigned u = __builtin_bit_cast(unsigned, f);
  u = (u + 0x7fffu + ((u >> 16) & 1u)) >> 16;
  return (unsigned short)u;
}

DEV f32x4 mfma16(bf16x8 a, bf16x8 b, f32x4 c) {
  return __builtin_amdgcn_mfma_f32_16x16x32_bf16(a, b, c, 0, 0, 0);
}

// ---------------- fp32 -> bf16 weight conversion (Whh for the 4 LSTM layers) ----
struct ConvJobs {
  const float* src[4];
  bf16* dst[4];
  int n[4];
  int cnt;
};

__global__ void convert_all(ConvJobs jobs) {
  long base = (long)blockIdx.x * blockDim.x + threadIdx.x;
  long stride = (long)gridDim.x * blockDim.x;
  for (int ji = 0; ji < jobs.cnt; ++ji) {
    const float* s = jobs.src[ji];
    bf16* d = jobs.dst[ji];
    long n4 = (long)jobs.n[ji] >> 2;
    for (long i = base; i < n4; i += stride) {
      f32x4 v = *(const f32x4*)(s + i * 4);
      short4v o;
#pragma unroll
      for (int j = 0; j < 4; ++j) o[j] = (short)f2bf(v[j]);
      *(short4v*)((short*)d + i * 4) = o;
    }
  }
}

// ---------------- embedding gather -> bf16 (E=256) ------------------------------
__global__ void embed_gather(const int* __restrict__ ids, const float* __restrict__ emb,
                             bf16* __restrict__ out, int rows, int tcols, int ids_stride) {
  long total = (long)rows * 64;  // 4 elems per item
  long stride = (long)gridDim.x * blockDim.x;
  for (long i = (long)blockIdx.x * blockDim.x + threadIdx.x; i < total; i += stride) {
    int row = (int)(i >> 6);
    int e = ((int)i & 63) * 4;
    int b = row / tcols;
    int t = row - b * tcols;
    int id = ids[b * ids_stride + t];
    f32x4 v = *(const f32x4*)(emb + (long)id * 256 + e);
    short4v o;
#pragma unroll
    for (int j = 0; j < 4; ++j) o[j] = (short)f2bf(v[j]);
    *(short4v*)((short*)out + (long)row * 256 + e) = o;
  }
}

// ---------------- zero out[:, 0, :] ---------------------------------------------
__global__ void zero_t0(float* __restrict__ out) {
  long total = 32l * 8000;  // float4 per item
  long stride = (long)gridDim.x * blockDim.x;
  f32x4 z{};
  for (long i = (long)blockIdx.x * blockDim.x + threadIdx.x; i < total; i += stride) {
    long b = i / 8000;
    long v = i - b * 8000;
    *(f32x4*)(out + b * 64 * 32000 + v * 4) = z;
  }
}

// ---------------- bf16 MFMA GEMM: C[M,N] = A[M,K] @ W[N,K]^T (+bias1+bias2) -----
// A bf16; W bf16 or fp32 (converted in staging). 128x128 tile, BK=64, 4 waves.
// affine_remap: C-row (b*63+t) written to out-row (b*64+t+1), N=32000.
__launch_bounds__(256)
__global__ void gemm_bf16(const bf16* __restrict__ A, const void* __restrict__ Wv, int b_fp32,
                          const float* __restrict__ bias1, const float* __restrict__ bias2,
                          float* __restrict__ C, int M, int N, int K, int affine_remap) {
  __shared__ __align__(16) bf16 As[128][64];
  __shared__ __align__(16) bf16 Bs[128][64];
  int nm = (M + 127) >> 7;
  int mt_blk = blockIdx.x % nm;   // m fastest -> concurrent blocks share W n-stripe in L2/LLC
  int nt_blk = blockIdx.x / nm;
  long m0 = (long)mt_blk * 128, n0 = (long)nt_blk * 128;
  int tid = threadIdx.x;
  int lane = tid & 63, wave = tid >> 6;
  int wm = wave & 1, wn = wave >> 1;
  int fl = lane & 15, fg = lane >> 4;
  const bf16* Wb = (const bf16*)Wv;
  const float* Wf = (const float*)Wv;
  f32x4 acc[4][4] = {};

  for (int k0 = 0; k0 < K; k0 += 64) {
    __syncthreads();
#pragma unroll
    for (int i = 0; i < 4; ++i) {
      int e = (i * 256 + tid) * 8;  // element index in 128x64 tile
      int row = e >> 6;
      int col = e & 63;
      long ar = m0 + row; if (ar >= M) ar = M - 1;
      *(bf16x8*)(&As[row][col]) = *(const bf16x8*)(A + ar * (long)K + k0 + col);
      long br = n0 + row; if (br >= N) br = N - 1;
      if (b_fp32) {
        const float* p = Wf + br * (long)K + k0 + col;
        f32x4 v0 = *(const f32x4*)p;
        f32x4 v1 = *(const f32x4*)(p + 4);
        short8v o;
#pragma unroll
        for (int j = 0; j < 4; ++j) { o[j] = (short)f2bf(v0[j]); o[j + 4] = (short)f2bf(v1[j]); }
        *(short8v*)(&Bs[row][col]) = o;
      } else {
        *(bf16x8*)(&Bs[row][col]) = *(const bf16x8*)(Wb + br * (long)K + k0 + col);
      }
    }
    __syncthreads();
#pragma unroll
    for (int kt = 0; kt < 2; ++kt) {
      bf16x8 af[4], bfr[4];
#pragma unroll
      for (int x = 0; x < 4; ++x)
        af[x] = *(const bf16x8*)(&As[wm * 64 + x * 16 + fl][kt * 32 + fg * 8]);
#pragma unroll
      for (int x = 0; x < 4; ++x)
        bfr[x] = *(const bf16x8*)(&Bs[wn * 64 + x * 16 + fl][kt * 32 + fg * 8]);
#pragma unroll
      for (int mi = 0; mi < 4; ++mi)
#pragma unroll
        for (int ni = 0; ni < 4; ++ni)
          acc[mi][ni] = mfma16(af[mi], bfr[ni], acc[mi][ni]);
    }
  }
  // epilogue: C/D layout col=lane&15, row=4*(lane>>4)+reg (guide-verified m89/m91)
#pragma unroll
  for (int mi = 0; mi < 4; ++mi) {
#pragma unroll
    for (int ni = 0; ni < 4; ++ni) {
#pragma unroll
      for (int r = 0; r < 4; ++r) {
        long row = m0 + wm * 64 + mi * 16 + fg * 4 + r;
        long col = n0 + wn * 64 + ni * 16 + fl;
        if (row < M && col < N) {
          float v = acc[mi][ni][r];
          if (bias1) v += bias1[col];
          if (bias2) v += bias2[col];
          long orow = row;
          if (affine_remap) {
            unsigned rr = (unsigned)row;
            unsigned bq = rr / 63u;
            orow = (long)bq * 64 + (rr - bq * 63u) + 1;
          }
          C[orow * (long)N + col] = v;
        }
      }
    }
  }
}

// ---------------- LSTM recurrence (one layer), cooperative, 64 blocks x 256 -----
// Block owns 8 hidden dims (32 gate rows). Weights live in registers as MFMA
// B-fragments (loaded once). h history stored bf16 (next step's MFMA A operand).
// c stays fp32 in registers. Cross-block sync per step = per-(step,block) flag
// on a private 128B line: producer does threadfence + release store; consumers
// poll all 64 flags (one lane per flag) + acquire fence. No central atomic.
__launch_bounds__(256)
__global__ void lstm_layer(const float* __restrict__ xg,   // [B,T,2048] incl. biases
                           const bf16* __restrict__ Whh,   // [2048,512] bf16
                           bf16* __restrict__ h_hist,      // [B,T,512] out
                           const bf16* __restrict__ h_init,// row b at h_init + b*hinit_stride
                           long hinit_stride,
                           const float* __restrict__ c_init, // [B,512]
                           float* __restrict__ c_final,      // [B,512]
                           int T, unsigned* __restrict__ flags, unsigned pass) {
  __shared__ float part[4][32][33];  // [wave][batch][gate-col], padded
  int tid = threadIdx.x;
  int lane = tid & 63, wave = tid >> 6;
  int fl = lane & 15, fg = lane >> 4;
  int n0 = blockIdx.x * 8;           // hidden dims [n0, n0+8)
  int b_t = tid & 31, d_t = tid >> 5;  // (batch, dim) for reduce/activation

  // preload weight fragments: wave w covers k in [w*128, w*128+128)
  bf16x8 wf[2][4];
#pragma unroll
  for (int nt = 0; nt < 2; ++nt) {
    int j = nt * 16 + fl;                       // gate-col 0..31
    long row = (long)(j >> 3) * 512 + n0 + (j & 7);  // gate gi = j>>3, dim = j&7
#pragma unroll
    for (int kt = 0; kt < 4; ++kt) {
      int k = (wave * 4 + kt) * 32 + fg * 8;
      wf[nt][kt] = *(const bf16x8*)(Whh + row * 512 + k);
    }
  }
  float c = c_init[(long)b_t * 512 + n0 + d_t];

  for (int s = 0; s < T; ++s) {
    // prefetch xg (independent of h) to overlap with the flag wait
    const float* xr = xg + ((long)b_t * T + s) * 2048 + n0 + d_t;
    float xv[4];
#pragma unroll
    for (int gi = 0; gi < 4; ++gi) xv[gi] = xr[(long)gi * 512];

    if (s > 0) {
      // wait for all 64 producer flags of step s-1 (lane l polls block l's flag)
      unsigned* f = flags + ((long)(s - 1) * 64 + lane) * 32;
      while (__hip_atomic_load(f, __ATOMIC_ACQUIRE, __HIP_MEMORY_SCOPE_AGENT) != pass) {}
      __builtin_amdgcn_fence(__ATOMIC_ACQUIRE, "agent");
    }

    const bf16* hp;
    long hstr;
    if (s == 0) { hp = h_init; hstr = hinit_stride; }
    else { hp = h_hist + (long)(s - 1) * 512; hstr = (long)T * 512; }

    f32x4 acc[2][2] = {};
#pragma unroll
    for (int kt = 0; kt < 4; ++kt) {
      int k = (wave * 4 + kt) * 32 + fg * 8;
      bf16x8 a0 = *(const bf16x8*)(hp + (long)fl * hstr + k);
      bf16x8 a1 = *(const bf16x8*)(hp + (long)(fl + 16) * hstr + k);
      acc[0][0] = mfma16(a0, wf[0][kt], acc[0][0]);
      acc[0][1] = mfma16(a0, wf[1][kt], acc[0][1]);
      acc[1][0] = mfma16(a1, wf[0][kt], acc[1][0]);
      acc[1][1] = mfma16(a1, wf[1][kt], acc[1][1]);
    }
#pragma unroll
    for (int mt = 0; mt < 2; ++mt)
#pragma unroll
      for (int nt = 0; nt < 2; ++nt)
#pragma unroll
        for (int r = 0; r < 4; ++r)
          part[wave][mt * 16 + fg * 4 + r][nt * 16 + fl] = acc[mt][nt][r];
    __syncthreads();

    // reduce 4 K-partials + activations; thread (b_t, d_t)
    float g4[4];
#pragma unroll
    for (int gi = 0; gi < 4; ++gi) {
      int j = gi * 8 + d_t;
      g4[gi] = part[0][b_t][j] + part[1][b_t][j] + part[2][b_t][j] + part[3][b_t][j] + xv[gi];
    }
    float ig = 1.f / (1.f + __expf(-g4[0]));
    float fg_ = 1.f / (1.f + __expf(-g4[1]));
    float gg = tanhf(g4[2]);
    float og = 1.f / (1.f + __expf(-g4[3]));
    c = fg_ * c + ig * gg;
    float h = og * tanhf(c);
    ((unsigned short*)h_hist)[((long)b_t * T + s) * 512 + n0 + d_t] = f2bf(h);

    __syncthreads();  // all h stores of this block done; also part[] reuse hazard
    if (s + 1 < T && tid == 0) {
      __threadfence();  // h slice visible device-wide before flag
      __hip_atomic_store(flags + ((long)s * 64 + blockIdx.x) * 32, pass,
                         __ATOMIC_RELEASE, __HIP_MEMORY_SCOPE_AGENT);
    }
  }
  c_final[(long)b_t * 512 + n0 + d_t] = c;
}

static void launch_lstm(const float* xg, const bf16* whh, bf16* hist, const bf16* hinit,
                        long hstride, const float* cinit, float* cfin, int T,
                        unsigned* flags, unsigned pass, hipStream_t stream) {
  void* args[10];
  args[0] = (void*)&xg;
  args[1] = (void*)&whh;
  args[2] = (void*)&hist;
  args[3] = (void*)&hinit;
  args[4] = (void*)&hstride;
  args[5] = (void*)&cinit;
  args[6] = (void*)&cfin;
  args[7] = (void*)&T;
  args[8] = (void*)&flags;
  args[9] = (void*)&pass;
  hipLaunchCooperativeKernel((void*)lstm_layer, dim3(64), dim3(256), args, 0, stream);
}

extern "C" void kernel_launch(void* const* d_in, const int* in_sizes, int n_in,
                              void* d_out, int out_size, void* d_ws, size_t ws_size,
                              hipStream_t stream) {
  (void)in_sizes; (void)n_in; (void)out_size; (void)ws_size;
  const int*   source   = (const int*)d_in[0];
  const int*   target   = (const int*)d_in[1];
  const float* enc_emb  = (const float*)d_in[2];
  const float* enc_Wih0 = (const float*)d_in[3];
  const float* enc_Whh0 = (const float*)d_in[4];
  const float* enc_bih0 = (const float*)d_in[5];
  const float* enc_bhh0 = (const float*)d_in[6];
  const float* enc_Wih1 = (const float*)d_in[7];
  const float* enc_Whh1 = (const float*)d_in[8];
  const float* enc_bih1 = (const float*)d_in[9];
  const float* enc_bhh1 = (const float*)d_in[10];
  const float* dec_emb  = (const float*)d_in[11];
  const float* dec_Wih0 = (const float*)d_in[12];
  const float* dec_Whh0 = (const float*)d_in[13];
  const float* dec_bih0 = (const float*)d_in[14];
  const float* dec_bhh0 = (const float*)d_in[15];
  const float* dec_Wih1 = (const float*)d_in[16];
  const float* dec_Whh1 = (const float*)d_in[17];
  const float* dec_bih1 = (const float*)d_in[18];
  const float* dec_bhh1 = (const float*)d_in[19];
  const float* aff_W    = (const float*)d_in[20];
  const float* aff_b    = (const float*)d_in[21];
  float* out = (float*)d_out;

  // workspace layout
  size_t off = 0;
  auto alc = [&](size_t bytes) {
    char* p = (char*)d_ws + off;
    off += (bytes + 255) & ~(size_t)255;
    return (void*)p;
  };
  unsigned* FLAGS = (unsigned*)alc((size_t)64 * 64 * 32 * 4);  // [step][block] on 128B lines
  bf16*  ZH  = (bf16*)alc(32 * 512 * 2);   // zero h_init (bf16)
  float* ZC  = (float*)alc(32 * 512 * 4);  // zero c_init (fp32)
  size_t zero_span = off;
  float* CE0 = (float*)alc(32 * 512 * 4);
  float* CE1 = (float*)alc(32 * 512 * 4);
  float* CD  = (float*)alc(32 * 512 * 4);
  bf16*  XE  = (bf16*)alc((size_t)2048 * 256 * 2);
  bf16*  XD  = (bf16*)alc((size_t)2016 * 256 * 2);
  bf16*  YE0 = (bf16*)alc((size_t)2048 * 512 * 2);
  bf16*  YE1 = (bf16*)alc((size_t)2048 * 512 * 2);
  bf16*  YD0 = (bf16*)alc((size_t)2016 * 512 * 2);
  bf16*  YD1 = (bf16*)alc((size_t)2016 * 512 * 2);
  float* XG  = (float*)alc((size_t)2048 * 2048 * 4);
  bf16*  WH0E = (bf16*)alc((size_t)2048 * 512 * 2);
  bf16*  WH1E = (bf16*)alc((size_t)2048 * 512 * 2);
  bf16*  WH0D = (bf16*)alc((size_t)2048 * 512 * 2);
  bf16*  WH1D = (bf16*)alc((size_t)2048 * 512 * 2);

  hipMemsetAsync(d_ws, 0, zero_span, stream);  // flags + zero inits

  ConvJobs cj;
  cj.src[0] = enc_Whh0; cj.dst[0] = WH0E; cj.n[0] = 2048 * 512;
  cj.src[1] = enc_Whh1; cj.dst[1] = WH1E; cj.n[1] = 2048 * 512;
  cj.src[2] = dec_Whh0; cj.dst[2] = WH0D; cj.n[2] = 2048 * 512;
  cj.src[3] = dec_Whh1; cj.dst[3] = WH1D; cj.n[3] = 2048 * 512;
  cj.cnt = 4;
  convert_all<<<dim3(1024), dim3(256), 0, stream>>>(cj);

  embed_gather<<<dim3(512), dim3(256), 0, stream>>>(source, enc_emb, XE, 2048, 64, 64);
  embed_gather<<<dim3(512), dim3(256), 0, stream>>>(target, dec_emb, XD, 2016, 63, 64);

  // encoder layer 0
  gemm_bf16<<<dim3(16 * 16), dim3(256), 0, stream>>>(XE, enc_Wih0, 1, enc_bih0, enc_bhh0,
                                                     XG, 2048, 2048, 256, 0);
  launch_lstm(XG, WH0E, YE0, ZH, 512, ZC, CE0, 64, FLAGS, 1u, stream);
  // encoder layer 1
  gemm_bf16<<<dim3(16 * 16), dim3(256), 0, stream>>>(YE0, enc_Wih1, 1, enc_bih1, enc_bhh1,
                                                     XG, 2048, 2048, 512, 0);
  launch_lstm(XG, WH1E, YE1, ZH, 512, ZC, CE1, 64, FLAGS, 2u, stream);
  // decoder layer 0 (init = encoder layer-0 finals)
  gemm_bf16<<<dim3(16 * 16), dim3(256), 0, stream>>>(XD, dec_Wih0, 1, dec_bih0, dec_bhh0,
                                                     XG, 2016, 2048, 256, 0);
  launch_lstm(XG, WH0D, YD0, YE0 + (size_t)63 * 512, 64 * 512, CE0, CD, 63, FLAGS, 3u, stream);
  // decoder layer 1 (init = encoder layer-1 finals)
  gemm_bf16<<<dim3(16 * 16), dim3(256), 0, stream>>>(YD0, dec_Wih1, 1, dec_bih1, dec_bhh1,
                                                     XG, 2016, 2048, 512, 0);
  launch_lstm(XG, WH1D, YD1, YE1 + (size_t)63 * 512, 64 * 512, CE1, CD, 63, FLAGS, 4u, stream);

  // output: out[:,0,:]=0, out[:,1:,:] = d1 @ aff_W.T + aff_b
  zero_t0<<<dim3(1000), dim3(256), 0, stream>>>(out);
  gemm_bf16<<<dim3(16 * 250), dim3(256), 0, stream>>>(YD1, aff_W, 1, aff_b, nullptr,
                                                      out, 2016, 32000, 512, 1);
}

// Round 3
// 2361.518 us; speedup vs baseline: 1.4234x; 1.4234x over previous
//
#include <hip/hip_runtime.h>
#include <hip/hip_bf16.h>

using bf16 = __hip_bfloat16;
typedef __bf16 bf16x8 __attribute__((ext_vector_type(8)));
typedef float f32x4 __attribute__((ext_vector_type(4)));
typedef short short4v __attribute__((ext_vector_type(4)));
typedef short short8v __attribute__((ext_vector_type(8)));

#define DEV __device__ __forceinline__

// B=32, S=64, T=64 (dec 63), V=32000, E=256, H=512, 4H=2048

DEV unsigned short f2bf(float f) {  // RNE float->bf16
  unsigned u = __builtin_bit_cast(unsigned, f);
  u = (u + 0x7fffu + ((u >> 16) & 1u)) >> 16;
  return (unsigned short)u;
}

DEV f32x4 mfma16(bf16x8 a, bf16x8 b, f32x4 c) {
  return __builtin_amdgcn_mfma_f32_16x16x32_bf16(a, b, c, 0, 0, 0);
}

// ---------------- fp32 -> bf16 weight conversion (8 matrices) -------------------
struct ConvJobs {
  const float* src[8];
  bf16* dst[8];
  int n[8];
  int cnt;
};

__global__ void convert_all(ConvJobs jobs) {
  long base = (long)blockIdx.x * blockDim.x + threadIdx.x;
  long stride = (long)gridDim.x * blockDim.x;
  for (int ji = 0; ji < jobs.cnt; ++ji) {
    const float* s = jobs.src[ji];
    bf16* d = jobs.dst[ji];
    long n4 = (long)jobs.n[ji] >> 2;
    for (long i = base; i < n4; i += stride) {
      f32x4 v = *(const f32x4*)(s + i * 4);
      short4v o;
#pragma unroll
      for (int j = 0; j < 4; ++j) o[j] = (short)f2bf(v[j]);
      *(short4v*)((short*)d + i * 4) = o;
    }
  }
}

// ---------------- embedding gather -> bf16, layout [T][B][256] ------------------
__global__ void embed_gather(const int* __restrict__ ids, const float* __restrict__ emb,
                             bf16* __restrict__ out, int rows, int ids_stride) {
  long total = (long)rows * 64;  // 4 elems per item
  long stride = (long)gridDim.x * blockDim.x;
  for (long i = (long)blockIdx.x * blockDim.x + threadIdx.x; i < total; i += stride) {
    int row = (int)(i >> 6);   // row = t*32 + b
    int e = ((int)i & 63) * 4;
    int b = row & 31;
    int t = row >> 5;
    int id = ids[b * ids_stride + t];
    f32x4 v = *(const f32x4*)(emb + (long)id * 256 + e);
    short4v o;
#pragma unroll
    for (int j = 0; j < 4; ++j) o[j] = (short)f2bf(v[j]);
    *(short4v*)((short*)out + (long)row * 256 + e) = o;
  }
}

// ---------------- zero out[:, 0, :] ---------------------------------------------
__global__ void zero_t0(float* __restrict__ out) {
  long total = 32l * 8000;  // float4 per item
  long stride = (long)gridDim.x * blockDim.x;
  f32x4 z{};
  for (long i = (long)blockIdx.x * blockDim.x + threadIdx.x; i < total; i += stride) {
    long b = i / 8000;
    long v = i - b * 8000;
    *(f32x4*)(out + b * 64 * 32000 + v * 4) = z;
  }
}

// ---------------- bf16 MFMA GEMM (used for the final affine only) ---------------
// C[M,N] = A[M,K] @ W[N,K]^T (+bias). A bf16 rows; W fp32 converted in staging.
// affine_remap: A-row r = t*32+b -> out-row b*64+t+1, N=32000.
__launch_bounds__(256)
__global__ void gemm_bf16(const bf16* __restrict__ A, const void* __restrict__ Wv, int b_fp32,
                          const float* __restrict__ bias1, const float* __restrict__ bias2,
                          float* __restrict__ C, int M, int N, int K, int affine_remap) {
  __shared__ __align__(16) bf16 As[128][64];
  __shared__ __align__(16) bf16 Bs[128][64];
  int nm = (M + 127) >> 7;
  int mt_blk = blockIdx.x % nm;
  int nt_blk = blockIdx.x / nm;
  long m0 = (long)mt_blk * 128, n0 = (long)nt_blk * 128;
  int tid = threadIdx.x;
  int lane = tid & 63, wave = tid >> 6;
  int wm = wave & 1, wn = wave >> 1;
  int fl = lane & 15, fg = lane >> 4;
  const bf16* Wb = (const bf16*)Wv;
  const float* Wf = (const float*)Wv;
  f32x4 acc[4][4] = {};

  for (int k0 = 0; k0 < K; k0 += 64) {
    __syncthreads();
#pragma unroll
    for (int i = 0; i < 4; ++i) {
      int e = (i * 256 + tid) * 8;
      int row = e >> 6;
      int col = e & 63;
      long ar = m0 + row; if (ar >= M) ar = M - 1;
      *(bf16x8*)(&As[row][col]) = *(const bf16x8*)(A + ar * (long)K + k0 + col);
      long br = n0 + row; if (br >= N) br = N - 1;
      if (b_fp32) {
        const float* p = Wf + br * (long)K + k0 + col;
        f32x4 v0 = *(const f32x4*)p;
        f32x4 v1 = *(const f32x4*)(p + 4);
        short8v o;
#pragma unroll
        for (int j = 0; j < 4; ++j) { o[j] = (short)f2bf(v0[j]); o[j + 4] = (short)f2bf(v1[j]); }
        *(short8v*)(&Bs[row][col]) = o;
      } else {
        *(bf16x8*)(&Bs[row][col]) = *(const bf16x8*)(Wb + br * (long)K + k0 + col);
      }
    }
    __syncthreads();
#pragma unroll
    for (int kt = 0; kt < 2; ++kt) {
      bf16x8 af[4], bfr[4];
#pragma unroll
      for (int x = 0; x < 4; ++x)
        af[x] = *(const bf16x8*)(&As[wm * 64 + x * 16 + fl][kt * 32 + fg * 8]);
#pragma unroll
      for (int x = 0; x < 4; ++x)
        bfr[x] = *(const bf16x8*)(&Bs[wn * 64 + x * 16 + fl][kt * 32 + fg * 8]);
#pragma unroll
      for (int mi = 0; mi < 4; ++mi)
#pragma unroll
        for (int ni = 0; ni < 4; ++ni)
          acc[mi][ni] = mfma16(af[mi], bfr[ni], acc[mi][ni]);
    }
  }
#pragma unroll
  for (int mi = 0; mi < 4; ++mi) {
#pragma unroll
    for (int ni = 0; ni < 4; ++ni) {
#pragma unroll
      for (int r = 0; r < 4; ++r) {
        long row = m0 + wm * 64 + mi * 16 + fg * 4 + r;
        long col = n0 + wn * 64 + ni * 16 + fl;
        if (row < M && col < N) {
          float v = acc[mi][ni][r];
          if (bias1) v += bias1[col];
          if (bias2) v += bias2[col];
          long orow = row;
          if (affine_remap) orow = (long)(row & 31) * 64 + (row >> 5) + 1;
          C[orow * (long)N + col] = v;
        }
      }
    }
  }
}

// ---------------- fused 4-layer pipelined LSTM (cooperative, 256 blocks) --------
// Block (l, slc): layer l = blockIdx>>6, hidden slice n0 = (blockIdx&63)*8.
// gates = [Wih_l | Whh_l] @ [x_t ; h_{t-1}] + (bih+bhh). K = Kx+512, split over
// 4 waves; weights live in registers (wf). Diagonal schedule: enc0 @ d, enc1 @
// d-1, dec0 @ d-64, dec1 @ d-65; 128 diagonals, one low-contention sync each:
//   producers: 1 release-store to a private 128B flag line
//   block 0:   relaxed-polls all 256 flags (1 reader/line), acquire fence,
//              broadcasts epoch=d to 64 lines
//   others:    wave 0 spins on one wave-uniform epoch line (relaxed), then
//              block-wide acquire fence.
// h layout [T][32][512] bf16: step row contiguous; stores repacked via LDS.
struct FusedParams {
  const bf16* wih[4]; const bf16* whh[4];
  const float* bih[4]; const float* bhh[4];
  const bf16* x[4];       // XE, YE0, XD, YD0
  bf16* y[4];             // YE0, YE1, YD0, YD1
  const bf16* hinit[4];   // ZH, ZH, YE0+63*32*512, YE1+63*32*512
  const float* cinit[4];  // ZC, ZC, CE0, CE1
  float* cfin[4];         // CE0, CE1, CD, CD2
  unsigned* flags;        // [128][256] on 128B lines
  unsigned* epoch;        // [64] on 128B lines
};

__launch_bounds__(256)
__global__ void lstm_fused(FusedParams P) {
  __shared__ float part[4][32][33];
  __shared__ __align__(16) unsigned short h_sh[32][8];
  const int tid = threadIdx.x;
  const int lane = tid & 63, wave = tid >> 6;
  const int fl = lane & 15, fg = lane >> 4;
  const int l = blockIdx.x >> 6;
  const int slc = blockIdx.x & 63;
  const int n0 = slc * 8;
  const int b_t = tid & 31, d_t = tid >> 5;
  const int start = (l == 0) ? 0 : (l == 1) ? 1 : (l == 2) ? 64 : 65;
  const int T = (l < 2) ? 64 : 63;
  const int Kx = (l & 1) ? 512 : 256;
  const int span = (Kx + 512) >> 2;  // per-wave K span: 192 or 256
  const int ktc = span >> 5;         // 6 or 8
  const bf16* __restrict__ Wih = P.wih[l];
  const bf16* __restrict__ Whh = P.whh[l];
  const bf16* __restrict__ X = P.x[l];
  bf16* __restrict__ Y = P.y[l];
  const bf16* __restrict__ Hinit = P.hinit[l];
  unsigned* flags = P.flags;
  unsigned* epoch = P.epoch;

  float bsum[4];
#pragma unroll
  for (int gi = 0; gi < 4; ++gi)
    bsum[gi] = P.bih[l][gi * 512 + n0 + d_t] + P.bhh[l][gi * 512 + n0 + d_t];

  // weight fragments (static indices only — full unroll with guard)
  bf16x8 wf[2][8];
#pragma unroll
  for (int nt = 0; nt < 2; ++nt) {
    int j = nt * 16 + fl;                              // gate-col 0..31
    long row = (long)(j >> 3) * 512 + n0 + (j & 7);    // gate=j>>3, dim=j&7
#pragma unroll
    for (int kt = 0; kt < 8; ++kt) {
      if (kt < ktc) {
        int k = wave * span + kt * 32 + fg * 8;
        wf[nt][kt] = (k < Kx) ? *(const bf16x8*)(Wih + row * (long)Kx + k)
                              : *(const bf16x8*)(Whh + row * 512l + (k - Kx));
      }
    }
  }
  float c = 0.f;

  for (int d = 0; d < 128; ++d) {
    if (d > 0) {
      if (blockIdx.x == 0) {
        unsigned* f = flags + ((long)(d - 1) * 256 + wave * 64 + lane) * 32;
        while (__hip_atomic_load(f, __ATOMIC_RELAXED, __HIP_MEMORY_SCOPE_AGENT) == 0u) {}
        __syncthreads();
        __builtin_amdgcn_fence(__ATOMIC_ACQUIRE, "agent");
        if (tid < 64)
          __hip_atomic_store(epoch + tid * 32, (unsigned)d, __ATOMIC_RELEASE,
                             __HIP_MEMORY_SCOPE_AGENT);
      } else {
        if (wave == 0) {
          unsigned* e = epoch + (blockIdx.x & 63) * 32;
          while (__hip_atomic_load(e, __ATOMIC_RELAXED, __HIP_MEMORY_SCOPE_AGENT) <
                 (unsigned)d) {}
        }
        __syncthreads();
        __builtin_amdgcn_fence(__ATOMIC_ACQUIRE, "agent");
      }
    }

    int t = d - start;
    if (t >= 0 && t < T) {
      if (t == 0) c = P.cinit[l][(long)b_t * 512 + n0 + d_t];
      const bf16* hb = (t == 0) ? Hinit : (Y + (long)(t - 1) * 32 * 512);
      const bf16* xb = X + (long)t * 32 * Kx;

      f32x4 acc[2][2] = {};
#pragma unroll
      for (int kt = 0; kt < 8; ++kt) {
        if (kt < ktc) {
          int kk = wave * span + kt * 32;
          int k = kk + fg * 8;
          const bf16 *p0, *p1;
          if (kk < Kx) {
            p0 = xb + (long)fl * Kx + k;
            p1 = xb + (long)(fl + 16) * Kx + k;
          } else {
            p0 = hb + (long)fl * 512 + (k - Kx);
            p1 = hb + (long)(fl + 16) * 512 + (k - Kx);
          }
          bf16x8 a0 = *(const bf16x8*)p0;
          bf16x8 a1 = *(const bf16x8*)p1;
          acc[0][0] = mfma16(a0, wf[0][kt], acc[0][0]);
          acc[0][1] = mfma16(a0, wf[1][kt], acc[0][1]);
          acc[1][0] = mfma16(a1, wf[0][kt], acc[1][0]);
          acc[1][1] = mfma16(a1, wf[1][kt], acc[1][1]);
        }
      }
#pragma unroll
      for (int mt = 0; mt < 2; ++mt)
#pragma unroll
        for (int nt = 0; nt < 2; ++nt)
#pragma unroll
          for (int r = 0; r < 4; ++r)
            part[wave][mt * 16 + fg * 4 + r][nt * 16 + fl] = acc[mt][nt][r];
      __syncthreads();

      float g4[4];
#pragma unroll
      for (int gi = 0; gi < 4; ++gi) {
        int j = gi * 8 + d_t;
        g4[gi] = part[0][b_t][j] + part[1][b_t][j] + part[2][b_t][j] + part[3][b_t][j] +
                 bsum[gi];
      }
      float ig = 1.f / (1.f + __expf(-g4[0]));
      float ff = 1.f / (1.f + __expf(-g4[1]));
      float gg = tanhf(g4[2]);
      float og = 1.f / (1.f + __expf(-g4[3]));
      c = ff * c + ig * gg;
      float h = og * tanhf(c);
      h_sh[b_t][d_t] = f2bf(h);
      if (t == T - 1) P.cfin[l][(long)b_t * 512 + n0 + d_t] = c;
      __syncthreads();
      if (tid < 32)
        *(short8v*)((unsigned short*)Y + ((long)t * 32 + tid) * 512 + n0) =
            *(const short8v*)(&h_sh[tid][0]);
    }

    if (tid == 0)
      __hip_atomic_store(flags + ((long)d * 256 + blockIdx.x) * 32, 1u, __ATOMIC_RELEASE,
                         __HIP_MEMORY_SCOPE_AGENT);
  }
}

extern "C" void kernel_launch(void* const* d_in, const int* in_sizes, int n_in,
                              void* d_out, int out_size, void* d_ws, size_t ws_size,
                              hipStream_t stream) {
  (void)in_sizes; (void)n_in; (void)out_size; (void)ws_size;
  const int*   source   = (const int*)d_in[0];
  const int*   target   = (const int*)d_in[1];
  const float* enc_emb  = (const float*)d_in[2];
  const float* enc_Wih0 = (const float*)d_in[3];
  const float* enc_Whh0 = (const float*)d_in[4];
  const float* enc_bih0 = (const float*)d_in[5];
  const float* enc_bhh0 = (const float*)d_in[6];
  const float* enc_Wih1 = (const float*)d_in[7];
  const float* enc_Whh1 = (const float*)d_in[8];
  const float* enc_bih1 = (const float*)d_in[9];
  const float* enc_bhh1 = (const float*)d_in[10];
  const float* dec_emb  = (const float*)d_in[11];
  const float* dec_Wih0 = (const float*)d_in[12];
  const float* dec_Whh0 = (const float*)d_in[13];
  const float* dec_bih0 = (const float*)d_in[14];
  const float* dec_bhh0 = (const float*)d_in[15];
  const float* dec_Wih1 = (const float*)d_in[16];
  const float* dec_Whh1 = (const float*)d_in[17];
  const float* dec_bih1 = (const float*)d_in[18];
  const float* dec_bhh1 = (const float*)d_in[19];
  const float* aff_W    = (const float*)d_in[20];
  const float* aff_b    = (const float*)d_in[21];
  float* out = (float*)d_out;

  size_t off = 0;
  auto alc = [&](size_t bytes) {
    char* p = (char*)d_ws + off;
    off += (bytes + 255) & ~(size_t)255;
    return (void*)p;
  };
  unsigned* FLAGS = (unsigned*)alc((size_t)128 * 256 * 32 * 4);  // 4 MB
  unsigned* EPOCH = (unsigned*)alc((size_t)64 * 32 * 4);
  bf16*  ZH  = (bf16*)alc(32 * 512 * 2);
  float* ZC  = (float*)alc(32 * 512 * 4);
  size_t zero_span = off;
  float* CE0 = (float*)alc(32 * 512 * 4);
  float* CE1 = (float*)alc(32 * 512 * 4);
  float* CD  = (float*)alc(32 * 512 * 4);
  float* CD2 = (float*)alc(32 * 512 * 4);
  bf16*  XE  = (bf16*)alc((size_t)2048 * 256 * 2);   // [64][32][256]
  bf16*  XD  = (bf16*)alc((size_t)2016 * 256 * 2);   // [63][32][256]
  bf16*  YE0 = (bf16*)alc((size_t)2048 * 512 * 2);   // [64][32][512]
  bf16*  YE1 = (bf16*)alc((size_t)2048 * 512 * 2);
  bf16*  YD0 = (bf16*)alc((size_t)2016 * 512 * 2);   // [63][32][512]
  bf16*  YD1 = (bf16*)alc((size_t)2016 * 512 * 2);
  bf16*  WI0E = (bf16*)alc((size_t)2048 * 256 * 2);
  bf16*  WH0E = (bf16*)alc((size_t)2048 * 512 * 2);
  bf16*  WI1E = (bf16*)alc((size_t)2048 * 512 * 2);
  bf16*  WH1E = (bf16*)alc((size_t)2048 * 512 * 2);
  bf16*  WI0D = (bf16*)alc((size_t)2048 * 256 * 2);
  bf16*  WH0D = (bf16*)alc((size_t)2048 * 512 * 2);
  bf16*  WI1D = (bf16*)alc((size_t)2048 * 512 * 2);
  bf16*  WH1D = (bf16*)alc((size_t)2048 * 512 * 2);

  hipMemsetAsync(d_ws, 0, zero_span, stream);  // flags + epoch + zero inits

  ConvJobs cj;
  cj.src[0] = enc_Wih0; cj.dst[0] = WI0E; cj.n[0] = 2048 * 256;
  cj.src[1] = enc_Whh0; cj.dst[1] = WH0E; cj.n[1] = 2048 * 512;
  cj.src[2] = enc_Wih1; cj.dst[2] = WI1E; cj.n[2] = 2048 * 512;
  cj.src[3] = enc_Whh1; cj.dst[3] = WH1E; cj.n[3] = 2048 * 512;
  cj.src[4] = dec_Wih0; cj.dst[4] = WI0D; cj.n[4] = 2048 * 256;
  cj.src[5] = dec_Whh0; cj.dst[5] = WH0D; cj.n[5] = 2048 * 512;
  cj.src[6] = dec_Wih1; cj.dst[6] = WI1D; cj.n[6] = 2048 * 512;
  cj.src[7] = dec_Whh1; cj.dst[7] = WH1D; cj.n[7] = 2048 * 512;
  cj.cnt = 8;
  convert_all<<<dim3(1024), dim3(256), 0, stream>>>(cj);

  embed_gather<<<dim3(512), dim3(256), 0, stream>>>(source, enc_emb, XE, 2048, 64);
  embed_gather<<<dim3(512), dim3(256), 0, stream>>>(target, dec_emb, XD, 2016, 64);

  FusedParams P;
  P.wih[0] = WI0E; P.whh[0] = WH0E; P.bih[0] = enc_bih0; P.bhh[0] = enc_bhh0;
  P.wih[1] = WI1E; P.whh[1] = WH1E; P.bih[1] = enc_bih1; P.bhh[1] = enc_bhh1;
  P.wih[2] = WI0D; P.whh[2] = WH0D; P.bih[2] = dec_bih0; P.bhh[2] = dec_bhh0;
  P.wih[3] = WI1D; P.whh[3] = WH1D; P.bih[3] = dec_bih1; P.bhh[3] = dec_bhh1;
  P.x[0] = XE;  P.x[1] = YE0; P.x[2] = XD;  P.x[3] = YD0;
  P.y[0] = YE0; P.y[1] = YE1; P.y[2] = YD0; P.y[3] = YD1;
  P.hinit[0] = ZH; P.hinit[1] = ZH;
  P.hinit[2] = YE0 + (size_t)63 * 32 * 512;
  P.hinit[3] = YE1 + (size_t)63 * 32 * 512;
  P.cinit[0] = ZC;  P.cinit[1] = ZC;  P.cinit[2] = CE0; P.cinit[3] = CE1;
  P.cfin[0]  = CE0; P.cfin[1]  = CE1; P.cfin[2]  = CD;  P.cfin[3]  = CD2;
  P.flags = FLAGS; P.epoch = EPOCH;
  void* args[1] = {&P};
  hipLaunchCooperativeKernel((void*)lstm_fused, dim3(256), dim3(256), args, 0, stream);

  // output: out[:,0,:]=0, out[:,1:,:] = d1 @ aff_W.T + aff_b
  zero_t0<<<dim3(1000), dim3(256), 0, stream>>>(out);
  gemm_bf16<<<dim3(16 * 250), dim3(256), 0, stream>>>(YD1, aff_W, 1, aff_b, nullptr,
                                                      out, 2016, 32000, 512, 1);
}

// Round 4
// 943.309 us; speedup vs baseline: 3.5634x; 2.5034x over previous
//
#include <hip/hip_runtime.h>
#include <hip/hip_bf16.h>

using bf16 = __hip_bfloat16;
typedef __bf16 bf16x8 __attribute__((ext_vector_type(8)));
typedef float f32x4 __attribute__((ext_vector_type(4)));
typedef int i32x4 __attribute__((ext_vector_type(4)));
typedef short short4v __attribute__((ext_vector_type(4)));
typedef short short8v __attribute__((ext_vector_type(8)));

#define DEV __device__ __forceinline__

// B=32, S=64, T=64 (dec 63), V=32000, E=256, H=512, 4H=2048

DEV unsigned short f2bf(float f) {  // RNE float->bf16
  unsigned u = __builtin_bit_cast(unsigned, f);
  u = (u + 0x7fffu + ((u >> 16) & 1u)) >> 16;
  return (unsigned short)u;
}

DEV f32x4 mfma16(bf16x8 a, bf16x8 b, f32x4 c) {
  return __builtin_amdgcn_mfma_f32_16x16x32_bf16(a, b, c, 0, 0, 0);
}

// ---- LLC-coherent (bypass L1+L2) access helpers: no fences needed ------------
DEV void llc_load16(bf16x8* dst, const bf16* p) {  // issue only; caller waits vmcnt
  i32x4 r;
  asm volatile("global_load_dwordx4 %0, %1, off sc0 sc1" : "=v"(r) : "v"(p) : "memory");
  *dst = __builtin_bit_cast(bf16x8, r);
}
DEV void llc_store16(void* p, short8v v) {
  asm volatile("global_store_dwordx4 %0, %1, off sc0 sc1"
               :: "v"(p), "v"(__builtin_bit_cast(i32x4, v)) : "memory");
}
DEV void llc_store_f32(float* p, float v) {
  asm volatile("global_store_dword %0, %1, off sc0 sc1" :: "v"(p), "v"(v) : "memory");
}
DEV float llc_load_f32(const float* p) {
  float r;
  asm volatile("global_load_dword %0, %1, off sc0 sc1\n\ts_waitcnt vmcnt(0)"
               : "=v"(r) : "v"(p) : "memory");
  return r;
}
DEV void llc_store_flag(unsigned* p, unsigned v) {
  asm volatile("global_store_dword %0, %1, off sc0 sc1" :: "v"(p), "v"(v) : "memory");
}

// ---------------- fp32 -> bf16 weight conversion (8 matrices) -------------------
struct ConvJobs {
  const float* src[8];
  bf16* dst[8];
  int n[8];
  int cnt;
};

__global__ void convert_all(ConvJobs jobs) {
  long base = (long)blockIdx.x * blockDim.x + threadIdx.x;
  long stride = (long)gridDim.x * blockDim.x;
  for (int ji = 0; ji < jobs.cnt; ++ji) {
    const float* s = jobs.src[ji];
    bf16* d = jobs.dst[ji];
    long n4 = (long)jobs.n[ji] >> 2;
    for (long i = base; i < n4; i += stride) {
      f32x4 v = *(const f32x4*)(s + i * 4);
      short4v o;
#pragma unroll
      for (int j = 0; j < 4; ++j) o[j] = (short)f2bf(v[j]);
      *(short4v*)((short*)d + i * 4) = o;
    }
  }
}

// ---------------- embedding gather -> bf16, layout [T][B][256] ------------------
__global__ void embed_gather(const int* __restrict__ ids, const float* __restrict__ emb,
                             bf16* __restrict__ out, int rows, int ids_stride) {
  long total = (long)rows * 64;  // 4 elems per item
  long stride = (long)gridDim.x * blockDim.x;
  for (long i = (long)blockIdx.x * blockDim.x + threadIdx.x; i < total; i += stride) {
    int row = (int)(i >> 6);   // row = t*32 + b
    int e = ((int)i & 63) * 4;
    int b = row & 31;
    int t = row >> 5;
    int id = ids[b * ids_stride + t];
    f32x4 v = *(const f32x4*)(emb + (long)id * 256 + e);
    short4v o;
#pragma unroll
    for (int j = 0; j < 4; ++j) o[j] = (short)f2bf(v[j]);
    *(short4v*)((short*)out + (long)row * 256 + e) = o;
  }
}

// ---------------- zero out[:, 0, :] ---------------------------------------------
__global__ void zero_t0(float* __restrict__ out) {
  long total = 32l * 8000;  // float4 per item
  long stride = (long)gridDim.x * blockDim.x;
  f32x4 z{};
  for (long i = (long)blockIdx.x * blockDim.x + threadIdx.x; i < total; i += stride) {
    long b = i / 8000;
    long v = i - b * 8000;
    *(f32x4*)(out + b * 64 * 32000 + v * 4) = z;
  }
}

// ---------------- bf16 MFMA GEMM (used for the final affine only) ---------------
// C[M,N] = A[M,K] @ W[N,K]^T (+bias). A bf16 rows; W fp32 converted in staging.
// affine_remap: A-row r = t*32+b -> out-row b*64+t+1, N=32000.
__launch_bounds__(256)
__global__ void gemm_bf16(const bf16* __restrict__ A, const void* __restrict__ Wv, int b_fp32,
                          const float* __restrict__ bias1, const float* __restrict__ bias2,
                          float* __restrict__ C, int M, int N, int K, int affine_remap) {
  __shared__ __align__(16) bf16 As[128][64];
  __shared__ __align__(16) bf16 Bs[128][64];
  int nm = (M + 127) >> 7;
  int mt_blk = blockIdx.x % nm;
  int nt_blk = blockIdx.x / nm;
  long m0 = (long)mt_blk * 128, n0 = (long)nt_blk * 128;
  int tid = threadIdx.x;
  int lane = tid & 63, wave = tid >> 6;
  int wm = wave & 1, wn = wave >> 1;
  int fl = lane & 15, fg = lane >> 4;
  const bf16* Wb = (const bf16*)Wv;
  const float* Wf = (const float*)Wv;
  f32x4 acc[4][4] = {};

  for (int k0 = 0; k0 < K; k0 += 64) {
    __syncthreads();
#pragma unroll
    for (int i = 0; i < 4; ++i) {
      int e = (i * 256 + tid) * 8;
      int row = e >> 6;
      int col = e & 63;
      long ar = m0 + row; if (ar >= M) ar = M - 1;
      *(bf16x8*)(&As[row][col]) = *(const bf16x8*)(A + ar * (long)K + k0 + col);
      long br = n0 + row; if (br >= N) br = N - 1;
      if (b_fp32) {
        const float* p = Wf + br * (long)K + k0 + col;
        f32x4 v0 = *(const f32x4*)p;
        f32x4 v1 = *(const f32x4*)(p + 4);
        short8v o;
#pragma unroll
        for (int j = 0; j < 4; ++j) { o[j] = (short)f2bf(v0[j]); o[j + 4] = (short)f2bf(v1[j]); }
        *(short8v*)(&Bs[row][col]) = o;
      } else {
        *(bf16x8*)(&Bs[row][col]) = *(const bf16x8*)(Wb + br * (long)K + k0 + col);
      }
    }
    __syncthreads();
#pragma unroll
    for (int kt = 0; kt < 2; ++kt) {
      bf16x8 af[4], bfr[4];
#pragma unroll
      for (int x = 0; x < 4; ++x)
        af[x] = *(const bf16x8*)(&As[wm * 64 + x * 16 + fl][kt * 32 + fg * 8]);
#pragma unroll
      for (int x = 0; x < 4; ++x)
        bfr[x] = *(const bf16x8*)(&Bs[wn * 64 + x * 16 + fl][kt * 32 + fg * 8]);
#pragma unroll
      for (int mi = 0; mi < 4; ++mi)
#pragma unroll
        for (int ni = 0; ni < 4; ++ni)
          acc[mi][ni] = mfma16(af[mi], bfr[ni], acc[mi][ni]);
    }
  }
#pragma unroll
  for (int mi = 0; mi < 4; ++mi) {
#pragma unroll
    for (int ni = 0; ni < 4; ++ni) {
#pragma unroll
      for (int r = 0; r < 4; ++r) {
        long row = m0 + wm * 64 + mi * 16 + fg * 4 + r;
        long col = n0 + wn * 64 + ni * 16 + fl;
        if (row < M && col < N) {
          float v = acc[mi][ni][r];
          if (bias1) v += bias1[col];
          if (bias2) v += bias2[col];
          long orow = row;
          if (affine_remap) orow = (long)(row & 31) * 64 + (row >> 5) + 1;
          C[orow * (long)N + col] = v;
        }
      }
    }
  }
}

// ---------------- fused 4-layer dataflow LSTM (cooperative, 256 blocks) ---------
// Block (l, slc): layer l = blockIdx>>6, hidden slice n0 = (blockIdx&63)*8.
// gates = [Wih_l | Whh_l] @ [x_t ; h_{t-1}] + (bih+bhh); weights in registers.
// NO grid barrier / NO fences: each block free-runs its t-loop, gated only by
// per-(layer,step,slc) flags. All cross-block data (h, c_final, flags) moves
// through LLC via sc0 sc1 accesses; producer orders h-stores before its flag
// with s_waitcnt vmcnt(0). Own-block slice is covered by the intra-block
// barrier (own lane exempt from own-layer flag poll).
// Waits at step t: l=0: f[0][t-1] | l=1: f[1][t-1] + f[0][t]
//                  l=2: f[2][t-1] (t=0: f[0][63]) | l=3: f[3][t-1] (t=0: f[1][63]) + f[2][t]
struct FusedParams {
  const bf16* wih[4]; const bf16* whh[4];
  const float* bih[4]; const float* bhh[4];
  const bf16* x[4];       // XE, YE0, XD, YD0
  bf16* y[4];             // YE0, YE1, YD0, YD1
  const bf16* hinit[4];   // ZH, ZH, YE0+63*32*512, YE1+63*32*512
  const float* cinit[4];  // ZC, ZC, CE0, CE1
  float* cfin[4];         // CE0, CE1, CD, CD2
  unsigned* flags;        // [4][64][64] each on a 128B line (2 MB)
};

DEV unsigned* FL(unsigned* flags, int l, int t) {
  return flags + ((long)(l * 64 + t) * 64) * 32;
}

__launch_bounds__(256)
__global__ void lstm_fused(FusedParams P) {
  __shared__ float part[4][32][33];
  __shared__ __align__(16) unsigned short h_sh[32][8];
  const int tid = threadIdx.x;
  const int lane = tid & 63, wave = tid >> 6;
  const int fl = lane & 15, fg = lane >> 4;
  const int l = blockIdx.x >> 6;
  const int slc = blockIdx.x & 63;
  const int n0 = slc * 8;
  const int b_t = tid & 31, d_t = tid >> 5;
  const int T = (l < 2) ? 64 : 63;
  const int Kx = (l & 1) ? 512 : 256;
  const int span = (Kx + 512) >> 2;  // per-wave K span: 192 or 256
  const int ktc = span >> 5;         // 6 or 8
  const bf16* __restrict__ Wih = P.wih[l];
  const bf16* __restrict__ Whh = P.whh[l];
  const bf16* __restrict__ X = P.x[l];
  bf16* __restrict__ Y = P.y[l];
  const bf16* __restrict__ Hinit = P.hinit[l];
  unsigned* flags = P.flags;

  float bsum[4];
#pragma unroll
  for (int gi = 0; gi < 4; ++gi)
    bsum[gi] = P.bih[l][gi * 512 + n0 + d_t] + P.bhh[l][gi * 512 + n0 + d_t];

  // weight fragments (normal cached loads; read-once)
  bf16x8 wf[2][8];
#pragma unroll
  for (int nt = 0; nt < 2; ++nt) {
    int j = nt * 16 + fl;                              // gate-col 0..31
    long row = (long)(j >> 3) * 512 + n0 + (j & 7);    // gate=j>>3, dim=j&7
#pragma unroll
    for (int kt = 0; kt < 8; ++kt) {
      if (kt < ktc) {
        int k = wave * span + kt * 32 + fg * 8;
        wf[nt][kt] = (k < Kx) ? *(const bf16x8*)(Wih + row * (long)Kx + k)
                              : *(const bf16x8*)(Whh + row * 512l + (k - Kx));
      }
    }
  }
  float c = 0.f;

  for (int t = 0; t < T; ++t) {
    // ---- dependency wait (LLC flag poll, relaxed loads, no fences) ----
    const unsigned* fa = nullptr;
    const unsigned* fb = nullptr;
    bool ownA = false;
    if (t > 0) { fa = FL(flags, l, t - 1); ownA = true; }
    else if (l == 2) fa = FL(flags, 0, 63);
    else if (l == 3) fa = FL(flags, 1, 63);
    if (l == 1) fb = FL(flags, 0, t);
    else if (l == 3) fb = FL(flags, 2, t);
    if (fa || fb) {
      const unsigned* pa = fa ? fa + (long)lane * 32 : nullptr;
      const unsigned* pb = fb ? fb + (long)lane * 32 : nullptr;
      const bool skipA = ownA && (lane == slc);  // own slice ordered by block barrier
      while (true) {
        bool ok = true;
        if (pa && !skipA)
          ok &= (__hip_atomic_load(pa, __ATOMIC_RELAXED, __HIP_MEMORY_SCOPE_SYSTEM) != 0u);
        if (pb)
          ok &= (__hip_atomic_load(pb, __ATOMIC_RELAXED, __HIP_MEMORY_SCOPE_SYSTEM) != 0u);
        if (__all(ok)) break;
      }
    }
    if (t == 0) c = llc_load_f32(P.cinit[l] + (long)b_t * 512 + n0 + d_t);

    const bf16* hb = (t == 0) ? Hinit : (Y + (long)(t - 1) * 32 * 512);
    const bf16* xb = X + (long)t * 32 * Kx;

    // ---- issue all A-fragment loads (LLC), then one wait, then MFMA ----
    bf16x8 a0v[8], a1v[8];
#pragma unroll
    for (int kt = 0; kt < 8; ++kt) {
      if (kt < ktc) {
        int kk = wave * span + kt * 32;
        int k = kk + fg * 8;
        const bf16 *p0, *p1;
        if (kk < Kx) {
          p0 = xb + (long)fl * Kx + k;
          p1 = xb + (long)(fl + 16) * Kx + k;
        } else {
          p0 = hb + (long)fl * 512 + (k - Kx);
          p1 = hb + (long)(fl + 16) * 512 + (k - Kx);
        }
        llc_load16(&a0v[kt], p0);
        llc_load16(&a1v[kt], p1);
      }
    }
    asm volatile("s_waitcnt vmcnt(0)" ::: "memory");
    __builtin_amdgcn_sched_barrier(0);

    f32x4 acc[2][2] = {};
#pragma unroll
    for (int kt = 0; kt < 8; ++kt) {
      if (kt < ktc) {
        acc[0][0] = mfma16(a0v[kt], wf[0][kt], acc[0][0]);
        acc[0][1] = mfma16(a0v[kt], wf[1][kt], acc[0][1]);
        acc[1][0] = mfma16(a1v[kt], wf[0][kt], acc[1][0]);
        acc[1][1] = mfma16(a1v[kt], wf[1][kt], acc[1][1]);
      }
    }
#pragma unroll
    for (int mt = 0; mt < 2; ++mt)
#pragma unroll
      for (int nt = 0; nt < 2; ++nt)
#pragma unroll
        for (int r = 0; r < 4; ++r)
          part[wave][mt * 16 + fg * 4 + r][nt * 16 + fl] = acc[mt][nt][r];
    __syncthreads();

    float g4[4];
#pragma unroll
    for (int gi = 0; gi < 4; ++gi) {
      int j = gi * 8 + d_t;
      g4[gi] = part[0][b_t][j] + part[1][b_t][j] + part[2][b_t][j] + part[3][b_t][j] +
               bsum[gi];
    }
    float ig = 1.f / (1.f + __expf(-g4[0]));
    float ff = 1.f / (1.f + __expf(-g4[1]));
    float gg = tanhf(g4[2]);
    float og = 1.f / (1.f + __expf(-g4[3]));
    c = ff * c + ig * gg;
    float h = og * tanhf(c);
    h_sh[b_t][d_t] = f2bf(h);
    if (t == T - 1) llc_store_f32(P.cfin[l] + (long)b_t * 512 + n0 + d_t, c);
    __syncthreads();
    if (tid < 32)
      llc_store16((unsigned short*)Y + ((long)t * 32 + tid) * 512 + n0,
                  *(const short8v*)(&h_sh[tid][0]));
    asm volatile("s_waitcnt vmcnt(0)" ::: "memory");  // h (+c) globally visible
    __syncthreads();                                  // before flag AND before any
    if (tid == 0)                                     // wave reuses h_sh/part
      llc_store_flag(FL(flags, l, t) + (long)slc * 32, 1u);
  }
}

extern "C" void kernel_launch(void* const* d_in, const int* in_sizes, int n_in,
                              void* d_out, int out_size, void* d_ws, size_t ws_size,
                              hipStream_t stream) {
  (void)in_sizes; (void)n_in; (void)out_size; (void)ws_size;
  const int*   source   = (const int*)d_in[0];
  const int*   target   = (const int*)d_in[1];
  const float* enc_emb  = (const float*)d_in[2];
  const float* enc_Wih0 = (const float*)d_in[3];
  const float* enc_Whh0 = (const float*)d_in[4];
  const float* enc_bih0 = (const float*)d_in[5];
  const float* enc_bhh0 = (const float*)d_in[6];
  const float* enc_Wih1 = (const float*)d_in[7];
  const float* enc_Whh1 = (const float*)d_in[8];
  const float* enc_bih1 = (const float*)d_in[9];
  const float* enc_bhh1 = (const float*)d_in[10];
  const float* dec_emb  = (const float*)d_in[11];
  const float* dec_Wih0 = (const float*)d_in[12];
  const float* dec_Whh0 = (const float*)d_in[13];
  const float* dec_bih0 = (const float*)d_in[14];
  const float* dec_bhh0 = (const float*)d_in[15];
  const float* dec_Wih1 = (const float*)d_in[16];
  const float* dec_Whh1 = (const float*)d_in[17];
  const float* dec_bih1 = (const float*)d_in[18];
  const float* dec_bhh1 = (const float*)d_in[19];
  const float* aff_W    = (const float*)d_in[20];
  const float* aff_b    = (const float*)d_in[21];
  float* out = (float*)d_out;

  size_t off = 0;
  auto alc = [&](size_t bytes) {
    char* p = (char*)d_ws + off;
    off += (bytes + 255) & ~(size_t)255;
    return (void*)p;
  };
  unsigned* FLAGS = (unsigned*)alc((size_t)4 * 64 * 64 * 32 * 4);  // 2 MB
  bf16*  ZH  = (bf16*)alc(32 * 512 * 2);
  float* ZC  = (float*)alc(32 * 512 * 4);
  size_t zero_span = off;
  float* CE0 = (float*)alc(32 * 512 * 4);
  float* CE1 = (float*)alc(32 * 512 * 4);
  float* CD  = (float*)alc(32 * 512 * 4);
  float* CD2 = (float*)alc(32 * 512 * 4);
  bf16*  XE  = (bf16*)alc((size_t)2048 * 256 * 2);   // [64][32][256]
  bf16*  XD  = (bf16*)alc((size_t)2016 * 256 * 2);   // [63][32][256]
  bf16*  YE0 = (bf16*)alc((size_t)2048 * 512 * 2);   // [64][32][512]
  bf16*  YE1 = (bf16*)alc((size_t)2048 * 512 * 2);
  bf16*  YD0 = (bf16*)alc((size_t)2016 * 512 * 2);   // [63][32][512]
  bf16*  YD1 = (bf16*)alc((size_t)2016 * 512 * 2);
  bf16*  WI0E = (bf16*)alc((size_t)2048 * 256 * 2);
  bf16*  WH0E = (bf16*)alc((size_t)2048 * 512 * 2);
  bf16*  WI1E = (bf16*)alc((size_t)2048 * 512 * 2);
  bf16*  WH1E = (bf16*)alc((size_t)2048 * 512 * 2);
  bf16*  WI0D = (bf16*)alc((size_t)2048 * 256 * 2);
  bf16*  WH0D = (bf16*)alc((size_t)2048 * 512 * 2);
  bf16*  WI1D = (bf16*)alc((size_t)2048 * 512 * 2);
  bf16*  WH1D = (bf16*)alc((size_t)2048 * 512 * 2);

  hipMemsetAsync(d_ws, 0, zero_span, stream);  // flags + zero inits

  ConvJobs cj;
  cj.src[0] = enc_Wih0; cj.dst[0] = WI0E; cj.n[0] = 2048 * 256;
  cj.src[1] = enc_Whh0; cj.dst[1] = WH0E; cj.n[1] = 2048 * 512;
  cj.src[2] = enc_Wih1; cj.dst[2] = WI1E; cj.n[2] = 2048 * 512;
  cj.src[3] = enc_Whh1; cj.dst[3] = WH1E; cj.n[3] = 2048 * 512;
  cj.src[4] = dec_Wih0; cj.dst[4] = WI0D; cj.n[4] = 2048 * 256;
  cj.src[5] = dec_Whh0; cj.dst[5] = WH0D; cj.n[5] = 2048 * 512;
  cj.src[6] = dec_Wih1; cj.dst[6] = WI1D; cj.n[6] = 2048 * 512;
  cj.src[7] = dec_Whh1; cj.dst[7] = WH1D; cj.n[7] = 2048 * 512;
  cj.cnt = 8;
  convert_all<<<dim3(1024), dim3(256), 0, stream>>>(cj);

  embed_gather<<<dim3(512), dim3(256), 0, stream>>>(source, enc_emb, XE, 2048, 64);
  embed_gather<<<dim3(512), dim3(256), 0, stream>>>(target, dec_emb, XD, 2016, 64);

  FusedParams P;
  P.wih[0] = WI0E; P.whh[0] = WH0E; P.bih[0] = enc_bih0; P.bhh[0] = enc_bhh0;
  P.wih[1] = WI1E; P.whh[1] = WH1E; P.bih[1] = enc_bih1; P.bhh[1] = enc_bhh1;
  P.wih[2] = WI0D; P.whh[2] = WH0D; P.bih[2] = dec_bih0; P.bhh[2] = dec_bhh0;
  P.wih[3] = WI1D; P.whh[3] = WH1D; P.bih[3] = dec_bih1; P.bhh[3] = dec_bhh1;
  P.x[0] = XE;  P.x[1] = YE0; P.x[2] = XD;  P.x[3] = YD0;
  P.y[0] = YE0; P.y[1] = YE1; P.y[2] = YD0; P.y[3] = YD1;
  P.hinit[0] = ZH; P.hinit[1] = ZH;
  P.hinit[2] = YE0 + (size_t)63 * 32 * 512;
  P.hinit[3] = YE1 + (size_t)63 * 32 * 512;
  P.cinit[0] = ZC;  P.cinit[1] = ZC;  P.cinit[2] = CE0; P.cinit[3] = CE1;
  P.cfin[0]  = CE0; P.cfin[1]  = CE1; P.cfin[2]  = CD;  P.cfin[3]  = CD2;
  P.flags = FLAGS;
  void* args[1] = {&P};
  hipLaunchCooperativeKernel((void*)lstm_fused, dim3(256), dim3(256), args, 0, stream);

  // output: out[:,0,:]=0, out[:,1:,:] = d1 @ aff_W.T + aff_b
  zero_t0<<<dim3(1000), dim3(256), 0, stream>>>(out);
  gemm_bf16<<<dim3(16 * 250), dim3(256), 0, stream>>>(YD1, aff_W, 1, aff_b, nullptr,
                                                      out, 2016, 32000, 512, 1);
}

// Round 5
// 768.444 us; speedup vs baseline: 4.3743x; 1.2276x over previous
//
#include <hip/hip_runtime.h>
#include <hip/hip_bf16.h>

using bf16 = __hip_bfloat16;
typedef __bf16 bf16x8 __attribute__((ext_vector_type(8)));
typedef float f32x4 __attribute__((ext_vector_type(4)));
typedef int i32x4 __attribute__((ext_vector_type(4)));
typedef short short4v __attribute__((ext_vector_type(4)));
typedef short short8v __attribute__((ext_vector_type(8)));

#define DEV __device__ __forceinline__

// B=32, S=64, T=64 (dec 63), V=32000, E=256, H=512, 4H=2048

DEV unsigned short f2bf(float f) {  // RNE float->bf16
  unsigned u = __builtin_bit_cast(unsigned, f);
  u = (u + 0x7fffu + ((u >> 16) & 1u)) >> 16;
  return (unsigned short)u;
}

DEV f32x4 mfma16(bf16x8 a, bf16x8 b, f32x4 c) {
  return __builtin_amdgcn_mfma_f32_16x16x32_bf16(a, b, c, 0, 0, 0);
}

// ---- LLC-coherent (bypass L1+L2) access helpers: no fences needed ------------
DEV void llc_load16(bf16x8* dst, const bf16* p) {  // issue only; caller waits vmcnt
  i32x4 r;
  asm volatile("global_load_dwordx4 %0, %1, off sc0 sc1" : "=v"(r) : "v"(p) : "memory");
  *dst = __builtin_bit_cast(bf16x8, r);
}
DEV void llc_store16(void* p, short8v v) {
  asm volatile("global_store_dwordx4 %0, %1, off sc0 sc1"
               :: "v"(p), "v"(__builtin_bit_cast(i32x4, v)) : "memory");
}
DEV void llc_store_f32(float* p, float v) {
  asm volatile("global_store_dword %0, %1, off sc0 sc1" :: "v"(p), "v"(v) : "memory");
}
DEV float llc_load_f32(const float* p) {
  float r;
  asm volatile("global_load_dword %0, %1, off sc0 sc1\n\ts_waitcnt vmcnt(0)"
               : "=v"(r) : "v"(p) : "memory");
  return r;
}
DEV void llc_store_flag(unsigned* p, unsigned v) {
  asm volatile("global_store_dword %0, %1, off sc0 sc1" :: "v"(p), "v"(v) : "memory");
}

// poll: check first (fast path), s_sleep backoff only when not ready
DEV void poll16(const unsigned* base, int wave, int lane) {
  const unsigned* p = base + (long)(wave * 16 + (lane & 15)) * 32;
  while (true) {
    unsigned v = __hip_atomic_load(p, __ATOMIC_RELAXED, __HIP_MEMORY_SCOPE_SYSTEM);
    if (__all(v != 0u)) break;
    __builtin_amdgcn_s_sleep(1);
  }
}
DEV void poll64(const unsigned* base, int lane) {
  const unsigned* p = base + (long)lane * 32;
  while (true) {
    unsigned v = __hip_atomic_load(p, __ATOMIC_RELAXED, __HIP_MEMORY_SCOPE_SYSTEM);
    if (__all(v != 0u)) break;
    __builtin_amdgcn_s_sleep(1);
  }
}

// ---------------- fp32 -> bf16 weight conversion --------------------------------
struct ConvJobs {
  const float* src[9];
  bf16* dst[9];
  int n[9];
  int cnt;
};

__global__ void convert_all(ConvJobs jobs) {
  long base = (long)blockIdx.x * blockDim.x + threadIdx.x;
  long stride = (long)gridDim.x * blockDim.x;
  for (int ji = 0; ji < jobs.cnt; ++ji) {
    const float* s = jobs.src[ji];
    bf16* d = jobs.dst[ji];
    long n4 = (long)jobs.n[ji] >> 2;
    for (long i = base; i < n4; i += stride) {
      f32x4 v = *(const f32x4*)(s + i * 4);
      short4v o;
#pragma unroll
      for (int j = 0; j < 4; ++j) o[j] = (short)f2bf(v[j]);
      *(short4v*)((short*)d + i * 4) = o;
    }
  }
}

// ---------------- embedding gather -> bf16, layout [T][B][256] ------------------
__global__ void embed_gather(const int* __restrict__ ids, const float* __restrict__ emb,
                             bf16* __restrict__ out, int rows, int ids_stride) {
  long total = (long)rows * 64;  // 4 elems per item
  long stride = (long)gridDim.x * blockDim.x;
  for (long i = (long)blockIdx.x * blockDim.x + threadIdx.x; i < total; i += stride) {
    int row = (int)(i >> 6);   // row = t*32 + b
    int e = ((int)i & 63) * 4;
    int b = row & 31;
    int t = row >> 5;
    int id = ids[b * ids_stride + t];
    f32x4 v = *(const f32x4*)(emb + (long)id * 256 + e);
    short4v o;
#pragma unroll
    for (int j = 0; j < 4; ++j) o[j] = (short)f2bf(v[j]);
    *(short4v*)((short*)out + (long)row * 256 + e) = o;
  }
}

// ---------------- zero out[:, 0, :] ---------------------------------------------
__global__ void zero_t0(float* __restrict__ out) {
  long total = 32l * 8000;  // float4 per item
  long stride = (long)gridDim.x * blockDim.x;
  f32x4 z{};
  for (long i = (long)blockIdx.x * blockDim.x + threadIdx.x; i < total; i += stride) {
    long b = i / 8000;
    long v = i - b * 8000;
    *(f32x4*)(out + b * 64 * 32000 + v * 4) = z;
  }
}

// ---------------- bf16 MFMA GEMM (final affine) ---------------------------------
// C[M,N] = A[M,K] @ W[N,K]^T (+bias). W bf16 (preconverted) or fp32 (in-staging).
// affine_remap: A-row r = t*32+b -> out-row b*64+t+1, N=32000.
__launch_bounds__(256)
__global__ void gemm_bf16(const bf16* __restrict__ A, const void* __restrict__ Wv, int b_fp32,
                          const float* __restrict__ bias1, const float* __restrict__ bias2,
                          float* __restrict__ C, int M, int N, int K, int affine_remap) {
  __shared__ __align__(16) bf16 As[128][64];
  __shared__ __align__(16) bf16 Bs[128][64];
  int nm = (M + 127) >> 7;
  int mt_blk = blockIdx.x % nm;
  int nt_blk = blockIdx.x / nm;
  long m0 = (long)mt_blk * 128, n0 = (long)nt_blk * 128;
  int tid = threadIdx.x;
  int lane = tid & 63, wave = tid >> 6;
  int wm = wave & 1, wn = wave >> 1;
  int fl = lane & 15, fg = lane >> 4;
  const bf16* Wb = (const bf16*)Wv;
  const float* Wf = (const float*)Wv;
  f32x4 acc[4][4] = {};

  for (int k0 = 0; k0 < K; k0 += 64) {
    __syncthreads();
#pragma unroll
    for (int i = 0; i < 4; ++i) {
      int e = (i * 256 + tid) * 8;
      int row = e >> 6;
      int col = e & 63;
      long ar = m0 + row; if (ar >= M) ar = M - 1;
      *(bf16x8*)(&As[row][col]) = *(const bf16x8*)(A + ar * (long)K + k0 + col);
      long br = n0 + row; if (br >= N) br = N - 1;
      if (b_fp32) {
        const float* p = Wf + br * (long)K + k0 + col;
        f32x4 v0 = *(const f32x4*)p;
        f32x4 v1 = *(const f32x4*)(p + 4);
        short8v o;
#pragma unroll
        for (int j = 0; j < 4; ++j) { o[j] = (short)f2bf(v0[j]); o[j + 4] = (short)f2bf(v1[j]); }
        *(short8v*)(&Bs[row][col]) = o;
      } else {
        *(bf16x8*)(&Bs[row][col]) = *(const bf16x8*)(Wb + br * (long)K + k0 + col);
      }
    }
    __syncthreads();
#pragma unroll
    for (int kt = 0; kt < 2; ++kt) {
      bf16x8 af[4], bfr[4];
#pragma unroll
      for (int x = 0; x < 4; ++x)
        af[x] = *(const bf16x8*)(&As[wm * 64 + x * 16 + fl][kt * 32 + fg * 8]);
#pragma unroll
      for (int x = 0; x < 4; ++x)
        bfr[x] = *(const bf16x8*)(&Bs[wn * 64 + x * 16 + fl][kt * 32 + fg * 8]);
#pragma unroll
      for (int mi = 0; mi < 4; ++mi)
#pragma unroll
        for (int ni = 0; ni < 4; ++ni)
          acc[mi][ni] = mfma16(af[mi], bfr[ni], acc[mi][ni]);
    }
  }
#pragma unroll
  for (int mi = 0; mi < 4; ++mi) {
#pragma unroll
    for (int ni = 0; ni < 4; ++ni) {
#pragma unroll
      for (int r = 0; r < 4; ++r) {
        long row = m0 + wm * 64 + mi * 16 + fg * 4 + r;
        long col = n0 + wn * 64 + ni * 16 + fl;
        if (row < M && col < N) {
          float v = acc[mi][ni][r];
          if (bias1) v += bias1[col];
          if (bias2) v += bias2[col];
          long orow = row;
          if (affine_remap) orow = (long)(row & 31) * 64 + (row >> 5) + 1;
          C[orow * (long)N + col] = v;
        }
      }
    }
  }
}

// ---------------- fused 4-layer dataflow LSTM (cooperative, 256 blocks) ---------
// Block (l, slc): layer l = blockIdx>>6, hidden slice n0 = (blockIdx&63)*8.
// Wave w owns K-spans: x [w*Kx/4, +Kx/4) and h [w*128, +128). Critical-path
// structure per step:
//   x-phase (h-independent) BEFORE the h wait; wave-local 16-flag fan-in for h
//   (wave w's h span comes from producer blocks 16w..16w+15 only);
//   wave 0 alone does {h store -> vmcnt -> flag}, waves 1-3 run ahead.
// All cross-block data via sc0 sc1 (LLC-coherent), ordering by vmcnt only.
struct FusedParams {
  const bf16* wih[4]; const bf16* whh[4];
  const float* bih[4]; const float* bhh[4];
  const bf16* x[4];       // XE, YE0, XD, YD0
  bf16* y[4];             // YE0, YE1, YD0, YD1
  const bf16* hinit[4];   // ZH, ZH, YE0+63*32*512, YE1+63*32*512
  const float* cinit[4];  // ZC, ZC, CE0, CE1
  float* cfin[4];         // CE0, CE1, CD, CD2
  unsigned* flags;        // [4][64][64] each on a 128B line (2 MB)
};

DEV unsigned* FL(unsigned* flags, int l, int t) {
  return flags + ((long)(l * 64 + t) * 64) * 32;
}

__launch_bounds__(256)
__global__ void lstm_fused(FusedParams P) {
  __shared__ float part[4][32][33];
  __shared__ __align__(16) unsigned short h_sh[32][8];
  const int tid = threadIdx.x;
  const int lane = tid & 63, wave = tid >> 6;
  const int fl = lane & 15, fg = lane >> 4;
  const int l = blockIdx.x >> 6;
  const int slc = blockIdx.x & 63;
  const int n0 = slc * 8;
  const int b_t = tid & 31, d_t = tid >> 5;
  const int T = (l < 2) ? 64 : 63;
  const int Kx = (l & 1) ? 512 : 256;
  const int xspan = Kx >> 2;   // per-wave x span: 64 or 128
  const int ktx = xspan >> 5;  // 2 or 4
  const bf16* __restrict__ Wih = P.wih[l];
  const bf16* __restrict__ Whh = P.whh[l];
  const bf16* __restrict__ X = P.x[l];
  bf16* __restrict__ Y = P.y[l];
  const bf16* __restrict__ Hinit = P.hinit[l];
  unsigned* flags = P.flags;

  float bsum[4];
#pragma unroll
  for (int gi = 0; gi < 4; ++gi)
    bsum[gi] = P.bih[l][gi * 512 + n0 + d_t] + P.bhh[l][gi * 512 + n0 + d_t];

  // weight fragments in registers: gate-col j = nt*16+fl -> (gate j>>3, dim j&7)
  bf16x8 wfx[2][4], wfh[2][4];
#pragma unroll
  for (int nt = 0; nt < 2; ++nt) {
    int j = nt * 16 + fl;
    long row = (long)(j >> 3) * 512 + n0 + (j & 7);
#pragma unroll
    for (int kt = 0; kt < 4; ++kt) {
      if (kt < ktx)
        wfx[nt][kt] =
            *(const bf16x8*)(Wih + row * (long)Kx + wave * xspan + kt * 32 + fg * 8);
      wfh[nt][kt] = *(const bf16x8*)(Whh + row * 512l + wave * 128 + kt * 32 + fg * 8);
    }
  }
  float c = 0.f;

  for (int t = 0; t < T; ++t) {
    // ---- x phase (independent of own h; gated only by producer layer) ----
    const unsigned* fb = (l == 1) ? FL(flags, 0, t) : (l == 3) ? FL(flags, 2, t) : nullptr;
    if (fb) poll16(fb, wave, lane);

    const bf16* xb = X + (long)t * 32 * Kx;
    bf16x8 xa0[4], xa1[4];
#pragma unroll
    for (int kt = 0; kt < 4; ++kt) {
      if (kt < ktx) {
        int k = wave * xspan + kt * 32 + fg * 8;
        const bf16* p0 = xb + (long)fl * Kx + k;
        const bf16* p1 = xb + (long)(fl + 16) * Kx + k;
        if (l & 1) {
          llc_load16(&xa0[kt], p0);
          llc_load16(&xa1[kt], p1);
        } else {  // XE/XD precomputed in a prior dispatch: normal cached loads
          xa0[kt] = *(const bf16x8*)p0;
          xa1[kt] = *(const bf16x8*)p1;
        }
      }
    }
    asm volatile("s_waitcnt vmcnt(0)" ::: "memory");
    __builtin_amdgcn_sched_barrier(0);
    f32x4 acc[2][2] = {};
#pragma unroll
    for (int kt = 0; kt < 4; ++kt) {
      if (kt < ktx) {
        acc[0][0] = mfma16(xa0[kt], wfx[0][kt], acc[0][0]);
        acc[0][1] = mfma16(xa0[kt], wfx[1][kt], acc[0][1]);
        acc[1][0] = mfma16(xa1[kt], wfx[0][kt], acc[1][0]);
        acc[1][1] = mfma16(xa1[kt], wfx[1][kt], acc[1][1]);
      }
    }

    // ---- h phase: wave-local fan-in (16 producers per wave) ----
    if (t > 0) poll16(FL(flags, l, t - 1), wave, lane);
    else if (l == 2) poll64(FL(flags, 0, 63), lane);
    else if (l == 3) poll64(FL(flags, 1, 63), lane);
    if (t == 0) c = llc_load_f32(P.cinit[l] + (long)b_t * 512 + n0 + d_t);

    const bf16* hb = (t == 0) ? Hinit : (Y + (long)(t - 1) * 32 * 512);
    bf16x8 ha0[4], ha1[4];
#pragma unroll
    for (int kt = 0; kt < 4; ++kt) {
      int k = wave * 128 + kt * 32 + fg * 8;
      llc_load16(&ha0[kt], hb + (long)fl * 512 + k);
      llc_load16(&ha1[kt], hb + (long)(fl + 16) * 512 + k);
    }
    asm volatile("s_waitcnt vmcnt(0)" ::: "memory");
    __builtin_amdgcn_sched_barrier(0);
#pragma unroll
    for (int kt = 0; kt < 4; ++kt) {
      acc[0][0] = mfma16(ha0[kt], wfh[0][kt], acc[0][0]);
      acc[0][1] = mfma16(ha0[kt], wfh[1][kt], acc[0][1]);
      acc[1][0] = mfma16(ha1[kt], wfh[0][kt], acc[1][0]);
      acc[1][1] = mfma16(ha1[kt], wfh[1][kt], acc[1][1]);
    }
#pragma unroll
    for (int mt = 0; mt < 2; ++mt)
#pragma unroll
      for (int nt = 0; nt < 2; ++nt)
#pragma unroll
        for (int r = 0; r < 4; ++r)
          part[wave][mt * 16 + fg * 4 + r][nt * 16 + fl] = acc[mt][nt][r];
    __syncthreads();

    // reduce 4 K-partials + activations; thread (b_t, d_t)
    float g4[4];
#pragma unroll
    for (int gi = 0; gi < 4; ++gi) {
      int j = gi * 8 + d_t;
      g4[gi] = part[0][b_t][j] + part[1][b_t][j] + part[2][b_t][j] + part[3][b_t][j] +
               bsum[gi];
    }
    float ig = 1.f / (1.f + __expf(-g4[0]));
    float ff = 1.f / (1.f + __expf(-g4[1]));
    float gg = tanhf(g4[2]);
    float og = 1.f / (1.f + __expf(-g4[3]));
    c = ff * c + ig * gg;
    float h = og * tanhf(c);
    h_sh[b_t][d_t] = f2bf(h);
    if (t == T - 1) {
      llc_store_f32(P.cfin[l] + (long)b_t * 512 + n0 + d_t, c);
      asm volatile("s_waitcnt vmcnt(0)" ::: "memory");  // all waves drain c stores
    }
    __syncthreads();
    // wave 0 publishes h + flag; waves 1-3 run ahead into next step's x-phase
    if (wave == 0) {
      if (lane < 32)
        llc_store16((unsigned short*)Y + ((long)t * 32 + lane) * 512 + n0,
                    *(const short8v*)(&h_sh[lane][0]));
      asm volatile("s_waitcnt vmcnt(0)" ::: "memory");
      if (lane == 0)
        llc_store_flag(FL(flags, l, t) + (long)slc * 32, 1u);
      asm volatile("s_waitcnt vmcnt(0)" ::: "memory");  // flag drained before own re-poll
    }
  }
}

extern "C" void kernel_launch(void* const* d_in, const int* in_sizes, int n_in,
                              void* d_out, int out_size, void* d_ws, size_t ws_size,
                              hipStream_t stream) {
  (void)in_sizes; (void)n_in; (void)out_size;
  const int*   source   = (const int*)d_in[0];
  const int*   target   = (const int*)d_in[1];
  const float* enc_emb  = (const float*)d_in[2];
  const float* enc_Wih0 = (const float*)d_in[3];
  const float* enc_Whh0 = (const float*)d_in[4];
  const float* enc_bih0 = (const float*)d_in[5];
  const float* enc_bhh0 = (const float*)d_in[6];
  const float* enc_Wih1 = (const float*)d_in[7];
  const float* enc_Whh1 = (const float*)d_in[8];
  const float* enc_bih1 = (const float*)d_in[9];
  const float* enc_bhh1 = (const float*)d_in[10];
  const float* dec_emb  = (const float*)d_in[11];
  const float* dec_Wih0 = (const float*)d_in[12];
  const float* dec_Whh0 = (const float*)d_in[13];
  const float* dec_bih0 = (const float*)d_in[14];
  const float* dec_bhh0 = (const float*)d_in[15];
  const float* dec_Wih1 = (const float*)d_in[16];
  const float* dec_Whh1 = (const float*)d_in[17];
  const float* dec_bih1 = (const float*)d_in[18];
  const float* dec_bhh1 = (const float*)d_in[19];
  const float* aff_W    = (const float*)d_in[20];
  const float* aff_b    = (const float*)d_in[21];
  float* out = (float*)d_out;

  size_t off = 0;
  auto alc = [&](size_t bytes) {
    char* p = (char*)d_ws + off;
    off += (bytes + 255) & ~(size_t)255;
    return (void*)p;
  };
  unsigned* FLAGS = (unsigned*)alc((size_t)4 * 64 * 64 * 32 * 4);  // 2 MB
  bf16*  ZH  = (bf16*)alc(32 * 512 * 2);
  float* ZC  = (float*)alc(32 * 512 * 4);
  size_t zero_span = off;
  float* CE0 = (float*)alc(32 * 512 * 4);
  float* CE1 = (float*)alc(32 * 512 * 4);
  float* CD  = (float*)alc(32 * 512 * 4);
  float* CD2 = (float*)alc(32 * 512 * 4);
  bf16*  XE  = (bf16*)alc((size_t)2048 * 256 * 2);   // [64][32][256]
  bf16*  XD  = (bf16*)alc((size_t)2016 * 256 * 2);   // [63][32][256]
  bf16*  YE0 = (bf16*)alc((size_t)2048 * 512 * 2);   // [64][32][512]
  bf16*  YE1 = (bf16*)alc((size_t)2048 * 512 * 2);
  bf16*  YD0 = (bf16*)alc((size_t)2016 * 512 * 2);   // [63][32][512]
  bf16*  YD1 = (bf16*)alc((size_t)2016 * 512 * 2);
  bf16*  WI0E = (bf16*)alc((size_t)2048 * 256 * 2);
  bf16*  WH0E = (bf16*)alc((size_t)2048 * 512 * 2);
  bf16*  WI1E = (bf16*)alc((size_t)2048 * 512 * 2);
  bf16*  WH1E = (bf16*)alc((size_t)2048 * 512 * 2);
  bf16*  WI0D = (bf16*)alc((size_t)2048 * 256 * 2);
  bf16*  WH0D = (bf16*)alc((size_t)2048 * 512 * 2);
  bf16*  WI1D = (bf16*)alc((size_t)2048 * 512 * 2);
  bf16*  WH1D = (bf16*)alc((size_t)2048 * 512 * 2);
  bf16*  WAFF = (bf16*)alc((size_t)32000 * 512 * 2);  // 32.8 MB, optional
  bool use_waff = (off <= ws_size);

  hipMemsetAsync(d_ws, 0, zero_span, stream);  // flags + zero inits

  ConvJobs cj;
  cj.src[0] = enc_Wih0; cj.dst[0] = WI0E; cj.n[0] = 2048 * 256;
  cj.src[1] = enc_Whh0; cj.dst[1] = WH0E; cj.n[1] = 2048 * 512;
  cj.src[2] = enc_Wih1; cj.dst[2] = WI1E; cj.n[2] = 2048 * 512;
  cj.src[3] = enc_Whh1; cj.dst[3] = WH1E; cj.n[3] = 2048 * 512;
  cj.src[4] = dec_Wih0; cj.dst[4] = WI0D; cj.n[4] = 2048 * 256;
  cj.src[5] = dec_Whh0; cj.dst[5] = WH0D; cj.n[5] = 2048 * 512;
  cj.src[6] = dec_Wih1; cj.dst[6] = WI1D; cj.n[6] = 2048 * 512;
  cj.src[7] = dec_Whh1; cj.dst[7] = WH1D; cj.n[7] = 2048 * 512;
  cj.cnt = 8;
  if (use_waff) {
    cj.src[8] = aff_W; cj.dst[8] = WAFF; cj.n[8] = 32000 * 512; cj.cnt = 9;
  }
  convert_all<<<dim3(1024), dim3(256), 0, stream>>>(cj);

  embed_gather<<<dim3(512), dim3(256), 0, stream>>>(source, enc_emb, XE, 2048, 64);
  embed_gather<<<dim3(512), dim3(256), 0, stream>>>(target, dec_emb, XD, 2016, 64);

  FusedParams P;
  P.wih[0] = WI0E; P.whh[0] = WH0E; P.bih[0] = enc_bih0; P.bhh[0] = enc_bhh0;
  P.wih[1] = WI1E; P.whh[1] = WH1E; P.bih[1] = enc_bih1; P.bhh[1] = enc_bhh1;
  P.wih[2] = WI0D; P.whh[2] = WH0D; P.bih[2] = dec_bih0; P.bhh[2] = dec_bhh0;
  P.wih[3] = WI1D; P.whh[3] = WH1D; P.bih[3] = dec_bih1; P.bhh[3] = dec_bhh1;
  P.x[0] = XE;  P.x[1] = YE0; P.x[2] = XD;  P.x[3] = YD0;
  P.y[0] = YE0; P.y[1] = YE1; P.y[2] = YD0; P.y[3] = YD1;
  P.hinit[0] = ZH; P.hinit[1] = ZH;
  P.hinit[2] = YE0 + (size_t)63 * 32 * 512;
  P.hinit[3] = YE1 + (size_t)63 * 32 * 512;
  P.cinit[0] = ZC;  P.cinit[1] = ZC;  P.cinit[2] = CE0; P.cinit[3] = CE1;
  P.cfin[0]  = CE0; P.cfin[1]  = CE1; P.cfin[2]  = CD;  P.cfin[3]  = CD2;
  P.flags = FLAGS;
  void* args[1] = {&P};
  hipLaunchCooperativeKernel((void*)lstm_fused, dim3(256), dim3(256), args, 0, stream);

  // output: out[:,0,:]=0, out[:,1:,:] = d1 @ aff_W.T + aff_b
  zero_t0<<<dim3(1000), dim3(256), 0, stream>>>(out);
  if (use_waff)
    gemm_bf16<<<dim3(16 * 250), dim3(256), 0, stream>>>(YD1, WAFF, 0, aff_b, nullptr,
                                                        out, 2016, 32000, 512, 1);
  else
    gemm_bf16<<<dim3(16 * 250), dim3(256), 0, stream>>>(YD1, aff_W, 1, aff_b, nullptr,
                                                        out, 2016, 32000, 512, 1);
}